// Round 7
// baseline (344.846 us; speedup 1.0000x reference)
//
#include <hip/hip_runtime.h>
#include <math.h>

#define NEG_SLOPE 0.2f
#define BSHIFT 8            // nodes per bucket = 256 (requires N < 65536 for src packing)

__device__ __forceinline__ float leaky(float e) {
    return e > 0.f ? e : NEG_SLOPE * e;
}

// ---------------- CSR build: bucketed counting sort ----------------

__global__ __launch_bounds__(256) void bucket_count_kernel(
        const int* __restrict__ dst, int* __restrict__ bucketCnt, int E, int nbk) {
    __shared__ int cnt[256];
    int t = threadIdx.x;
    cnt[t] = 0;
    __syncthreads();
    for (int i = blockIdx.x * 256 + t; i < E; i += gridDim.x * 256)
        atomicAdd(&cnt[dst[i] >> BSHIFT], 1);
    __syncthreads();
    if (t < nbk && cnt[t] > 0) atomicAdd(&bucketCnt[t], cnt[t]);
}

__global__ __launch_bounds__(256) void bucket_scan_kernel(
        const int* __restrict__ bucketCnt, int* __restrict__ bucketOff,
        int* __restrict__ bucketCursor, int nbk) {
    __shared__ int s[256];
    int t = threadIdx.x;
    int v = (t < nbk) ? bucketCnt[t] : 0;
    s[t] = v;
    __syncthreads();
    for (int o = 1; o < 256; o <<= 1) {
        int x = (t >= o) ? s[t - o] : 0;
        __syncthreads();
        s[t] += x;
        __syncthreads();
    }
    if (t < nbk) {
        int excl = s[t] - v;
        bucketOff[t] = excl;
        bucketCursor[t] = excl;
    }
}

__global__ __launch_bounds__(256) void partition_kernel(
        const int* __restrict__ src, const int* __restrict__ dst,
        int* __restrict__ bucketCursor, int* __restrict__ pairs, int E, int nbk) {
    __shared__ int cnt[256];
    __shared__ int run[256];
    int t = threadIdx.x;
    int chunk = (E + gridDim.x - 1) / gridDim.x;
    int beg = blockIdx.x * chunk;
    int end = min(beg + chunk, E);
    cnt[t] = 0;
    __syncthreads();
    for (int i = beg + t; i < end; i += 256)
        atomicAdd(&cnt[dst[i] >> BSHIFT], 1);
    __syncthreads();
    if (t < nbk) run[t] = atomicAdd(&bucketCursor[t], cnt[t]);
    __syncthreads();
    for (int i = beg + t; i < end; i += 256) {
        int d = dst[i];
        int slot = atomicAdd(&run[d >> BSHIFT], 1);
        pairs[slot] = (src[i] << BSHIFT) | (d & 255);
    }
}

__global__ __launch_bounds__(256) void csr_build_kernel(
        const int* __restrict__ bucketOff, const int* __restrict__ pairs,
        int* __restrict__ off, int* __restrict__ csr_src, int N, int E, int nbk) {
    __shared__ int degl[256];
    __shared__ int s[256];
    __shared__ int cur[256];
    int t = threadIdx.x;
    int b = blockIdx.x;
    int n0 = b << BSHIFT;
    int nodecnt = min(256, N - n0);
    int ebeg = bucketOff[b];
    int eend = (b == nbk - 1) ? E : bucketOff[b + 1];

    degl[t] = 0;
    __syncthreads();
    for (int i = ebeg + t; i < eend; i += 256)
        atomicAdd(&degl[pairs[i] & 255], 1);
    __syncthreads();

    int v = degl[t];
    s[t] = v;
    __syncthreads();
    for (int o = 1; o < 256; o <<= 1) {
        int x = (t >= o) ? s[t - o] : 0;
        __syncthreads();
        s[t] += x;
        __syncthreads();
    }
    int excl = s[t] - v;
    if (t < nodecnt) off[n0 + t] = ebeg + excl;
    if (b == 0 && t == 0) off[N] = E;
    cur[t] = excl;
    __syncthreads();

    for (int i = ebeg + t; i < eend; i += 256) {
        int pk = pairs[i];
        int p = atomicAdd(&cur[pk & 255], 1);
        csr_src[ebeg + p] = pk >> BSHIFT;
    }
}

// ---------------- GEMM + alpha epilogue ----------------
// 8 nodes/wave. W (k-major, [k][64]) in LDS, conflict-free b32 reads.
// h accessed via wave-uniform (readfirstlane-asserted) row pointers so the
// compiler can use scalar loads / SGPR operands: inner loop = 4 ds_read +
// 32 v_fma per 4 k-values (fma density ~89% vs 47% with readlane bcast).

template <int CIN>
__global__ __launch_bounds__(256) void gemm_alpha_kernel(
        const float* __restrict__ h, const float* __restrict__ W,
        const float* __restrict__ a_src, const float* __restrict__ a_dst,
        float* __restrict__ hp, float* __restrict__ as_, float* __restrict__ ad_,
        int n) {
    constexpr int NPW = 8;
    __shared__ float Ws[CIN * 64];
    int t = threadIdx.x, wave = t >> 6, lane = t & 63;
    int node0 = blockIdx.x * 32 + wave * NPW;

    {
        const float4* W4 = (const float4*)W;
        float4* Ws4 = (float4*)Ws;
        constexpr int cnt4 = CIN * 16;
#pragma unroll
        for (int i = 0; i < cnt4 / 256; ++i) Ws4[i * 256 + t] = W4[i * 256 + t];
    }

    // wave-uniform row pointers (tail block clamps to n-1; writes are guarded)
    const float* hrow[NPW];
#pragma unroll
    for (int r = 0; r < NPW; ++r) {
        int nd = node0 + r;
        if (nd > n - 1) nd = n - 1;
        hrow[r] = h + (size_t)__builtin_amdgcn_readfirstlane(nd) * CIN;
    }
    __syncthreads();

    float acc[NPW];
#pragma unroll
    for (int r = 0; r < NPW; ++r) acc[r] = 0.f;

#pragma unroll 4
    for (int k0 = 0; k0 < CIN; k0 += 4) {
        float hk[NPW][4];
#pragma unroll
        for (int r = 0; r < NPW; ++r)
#pragma unroll
            for (int kk = 0; kk < 4; ++kk)
                hk[r][kk] = hrow[r][k0 + kk];
#pragma unroll
        for (int kk = 0; kk < 4; ++kk) {
            float w = Ws[(k0 + kk) * 64 + lane];
#pragma unroll
            for (int r = 0; r < NPW; ++r)
                acc[r] = fmaf(hk[r][kk], w, acc[r]);
        }
    }

    float asl = a_src[lane], adl = a_dst[lane];
#pragma unroll
    for (int r = 0; r < NPW; ++r) {
        int node = node0 + r;
        if (node >= n) break;
        hp[(size_t)node * 64 + lane] = acc[r];
        float vs = acc[r] * asl;
        float vd = acc[r] * adl;
#pragma unroll
        for (int o = 32; o > 0; o >>= 1) {
            vs += __shfl_xor(vs, o);
            vd += __shfl_xor(vd, o);
        }
        if (lane == 0) {
            as_[node] = vs;
            ad_[node] = vd;
        }
    }
}

// ---------------- per-dst segment softmax + weighted gather-sum ----------------
// One wave per node. NO cross-lane ops inside divergent-trip loops (R4 trap).
// Gather loop: 4 lane-groups x float4, 1-deep software pipeline (prefetch
// edge j+4's row while accumulating edge j) -> 8 loads in flight per wave.

__global__ __launch_bounds__(256) void agg_kernel(
        const float* __restrict__ hp,
        const float* __restrict__ as_, const float* __restrict__ ad_,
        const int* __restrict__ off, const int* __restrict__ csr_src,
        const float* __restrict__ bias, float* __restrict__ out, int n) {
    __shared__ float pw[4][64];
    __shared__ int ps[4][64];
    int t = threadIdx.x;
    int wave = t >> 6, lane = t & 63;
    int node = blockIdx.x * 4 + wave;
    if (node >= n) return;

    int beg = off[node], end = off[node + 1];
    int deg = end - beg;
    float adst = ad_[node];
    float e_self = leaky(as_[node] + adst);

    if (deg <= 64) {
        bool valid = lane < deg;
        int s = valid ? csr_src[beg + lane] : 0;
        float e = valid ? leaky(as_[s] + adst) : -3.4e38f;

        float m = e;
#pragma unroll
        for (int o = 32; o > 0; o >>= 1) m = fmaxf(m, __shfl_xor(m, o));
        m = fmaxf(m, e_self);

        float p = valid ? __expf(e - m) : 0.f;
        float pself = __expf(e_self - m);
        float se = p;
#pragma unroll
        for (int o = 32; o > 0; o >>= 1) se += __shfl_xor(se, o);
        se += pself;
        float inv = 1.0f / (se + 1e-16f);
        p *= inv;

        pw[wave][lane] = p;
        ps[wave][lane] = s;

        int group = lane >> 4, sub = lane & 15;
        const float4* hp4 = (const float4*)hp;

        float wself = (group == 0) ? pself * inv : 0.f;
        float4 hv = hp4[(size_t)node * 16 + sub];
        float4 acc;
        acc.x = wself * hv.x;
        acc.y = wself * hv.y;
        acc.z = wself * hv.z;
        acc.w = wself * hv.w;

        int j = group;
        float w0 = 0.f;
        float4 v0 = make_float4(0.f, 0.f, 0.f, 0.f);
        if (j < deg) {
            w0 = pw[wave][j];
            v0 = hp4[(size_t)ps[wave][j] * 16 + sub];
        }
        for (; j + 4 < deg; j += 4) {
            float w1 = pw[wave][j + 4];
            int s1 = ps[wave][j + 4];
            float4 v1 = hp4[(size_t)s1 * 16 + sub];
            acc.x = fmaf(w0, v0.x, acc.x);
            acc.y = fmaf(w0, v0.y, acc.y);
            acc.z = fmaf(w0, v0.z, acc.z);
            acc.w = fmaf(w0, v0.w, acc.w);
            w0 = w1;
            v0 = v1;
        }
        if (j < deg) {
            acc.x = fmaf(w0, v0.x, acc.x);
            acc.y = fmaf(w0, v0.y, acc.y);
            acc.z = fmaf(w0, v0.z, acc.z);
            acc.w = fmaf(w0, v0.w, acc.w);
        }

        // all lanes reconverged — xor-tree across the 4 groups
#pragma unroll
        for (int o = 16; o <= 32; o <<= 1) {
            acc.x += __shfl_xor(acc.x, o);
            acc.y += __shfl_xor(acc.y, o);
            acc.z += __shfl_xor(acc.z, o);
            acc.w += __shfl_xor(acc.w, o);
        }

        float4 b4 = ((const float4*)bias)[sub];
        float4 r;
        r.x = acc.x + b4.x; r.x = r.x > 0.f ? r.x : 0.f;
        r.y = acc.y + b4.y; r.y = r.y > 0.f ? r.y : 0.f;
        r.z = acc.z + b4.z; r.z = r.z > 0.f ? r.z : 0.f;
        r.w = acc.w + b4.w; r.w = r.w > 0.f ? r.w : 0.f;
        if (group == 0) ((float4*)out)[(size_t)node * 16 + sub] = r;
    } else {
        float mymax = e_self;
        for (int i = beg + lane; i < end; i += 64) {
            int s = csr_src[i];
            mymax = fmaxf(mymax, leaky(as_[s] + adst));
        }
#pragma unroll
        for (int o = 32; o > 0; o >>= 1) mymax = fmaxf(mymax, __shfl_xor(mymax, o));
        float m = mymax;

        float se = 0.f;
        for (int i = beg + lane; i < end; i += 64) {
            int s = csr_src[i];
            se += __expf(leaky(as_[s] + adst) - m);
        }
#pragma unroll
        for (int o = 32; o > 0; o >>= 1) se += __shfl_xor(se, o);
        se += __expf(e_self - m);
        float inv = 1.0f / (se + 1e-16f);

        float acc = __expf(e_self - m) * inv * hp[(size_t)node * 64 + lane];
        for (int i = beg; i < end; ++i) {
            int s = csr_src[i];
            float w = __expf(leaky(as_[s] + adst) - m) * inv;
            acc = fmaf(w, hp[(size_t)s * 64 + lane], acc);
        }
        float r = acc + bias[lane];
        out[(size_t)node * 64 + lane] = r > 0.f ? r : 0.f;
    }
}

// ---------------- launch ----------------

extern "C" void kernel_launch(void* const* d_in, const int* in_sizes, int n_in,
                              void* d_out, int out_size, void* d_ws, size_t ws_size,
                              hipStream_t stream) {
    const float* x = (const float*)d_in[0];
    const int* edge_index = (const int*)d_in[1];
    const int N = in_sizes[0] / 128;
    const int E = in_sizes[1] / 2;
    const int NBK = (N + 255) >> BSHIFT;

    const float* W[3]    = {(const float*)d_in[4], (const float*)d_in[8],  (const float*)d_in[12]};
    const float* asrc[3] = {(const float*)d_in[5], (const float*)d_in[9],  (const float*)d_in[13]};
    const float* adst[3] = {(const float*)d_in[6], (const float*)d_in[10], (const float*)d_in[14]};
    const float* bias[3] = {(const float*)d_in[7], (const float*)d_in[11], (const float*)d_in[15]};

    char* ws = (char*)d_ws;
    size_t o = 0;
    auto alloc = [&](size_t bytes) {
        char* p = ws + o;
        o += (bytes + 255) & ~(size_t)255;
        return p;
    };
    int* bucketCnt    = (int*)alloc(256 * 4);
    int* bucketOff    = (int*)alloc(257 * 4);
    int* bucketCursor = (int*)alloc(256 * 4);
    int* pairs        = (int*)alloc((size_t)E * 4);
    int* off          = (int*)alloc((size_t)(N + 1) * 4);
    int* csr_src      = (int*)alloc((size_t)E * 4);
    float* as_        = (float*)alloc((size_t)N * 4);
    float* ad_        = (float*)alloc((size_t)N * 4);
    float* bufA       = (float*)alloc((size_t)N * 64 * 4);
    float* bufB       = (float*)alloc((size_t)N * 64 * 4);

    const int* srcp = edge_index;
    const int* dstp = edge_index + E;

    hipMemsetAsync(bucketCnt, 0, 256 * 4, stream);
    bucket_count_kernel<<<256, 256, 0, stream>>>(dstp, bucketCnt, E, NBK);
    bucket_scan_kernel<<<1, 256, 0, stream>>>(bucketCnt, bucketOff, bucketCursor, NBK);
    partition_kernel<<<256, 256, 0, stream>>>(srcp, dstp, bucketCursor, pairs, E, NBK);
    csr_build_kernel<<<NBK, 256, 0, stream>>>(bucketOff, pairs, off, csr_src, N, E, NBK);

    const float* hin = x;
    for (int l = 0; l < 3; ++l) {
        float* hp = bufA;
        float* hout = (l == 2) ? (float*)d_out : bufB;
        if (l == 0) {
            gemm_alpha_kernel<128><<<(N + 31) / 32, 256, 0, stream>>>(
                hin, W[l], asrc[l], adst[l], hp, as_, ad_, N);
        } else {
            gemm_alpha_kernel<64><<<(N + 31) / 32, 256, 0, stream>>>(
                hin, W[l], asrc[l], adst[l], hp, as_, ad_, N);
        }
        agg_kernel<<<(N + 3) / 4, 256, 0, stream>>>(
            hp, as_, ad_, off, csr_src, bias[l], hout, N);
        hin = hout;
    }
}